// Round 4
// baseline (259.951 us; speedup 1.0000x reference)
//
#include <hip/hip_runtime.h>
#include <hip/hip_bf16.h>

// T6 tensor-product attention, MI355X gfx950.
// B=2 S=2048 D=1024 H=16 DK=64 QR=6 R=2.
// R3: flash Q-tile 128 (halved staging/barriers, 2x MFMA per stage, masked-strip skip);
//     cast3 removed (proj GEMM converts fp32->bf16 during LDS staging);
//     both GEMMs use 64-wide N tiles (512 blocks); HW sin/cos in RoPE.

typedef __attribute__((ext_vector_type(8))) short short8;   // 8 bf16 = 4 VGPRs
typedef __attribute__((ext_vector_type(4))) float floatx4;  // 4 fp32 acc

#define MFMA16(a, b, c) __builtin_amdgcn_mfma_f32_16x16x32_bf16(a, b, c, 0, 0, 0)

__device__ __forceinline__ unsigned short bfbits(float x) {
    __hip_bfloat16 h = __float2bfloat16(x);
    return *(unsigned short*)&h;
}

// ---------------------------------------------------------------- pack all W^T into one contiguous
// bf16 region [2048 rows x 1024 cols], zero-padded, via LDS tile transpose (coalesced both sides).
// rows: [0,96)=AqT [96,480)=BqT [480,512)=0 | [512,544)=AkT [544,672)=BkT [672,768)=0 |
//       [768,800)=AvT [800,928)=BvT [928,1024)=0 | [1024,2048)=WoT
__device__ __forceinline__ float wsrc(int n, int k,
                                      const float* __restrict__ Aq, const float* __restrict__ Bq,
                                      const float* __restrict__ Ak, const float* __restrict__ Bk,
                                      const float* __restrict__ Av, const float* __restrict__ Bv,
                                      const float* __restrict__ Wo) {
    if (n < 96) return Aq[(size_t)k * 96 + n];
    if (n < 480) return Bq[(size_t)k * 384 + (n - 96)];
    if (n < 512) return 0.f;
    if (n < 544) return Ak[(size_t)k * 32 + (n - 512)];
    if (n < 672) return Bk[(size_t)k * 128 + (n - 544)];
    if (n < 768) return 0.f;
    if (n < 800) return Av[(size_t)k * 32 + (n - 768)];
    if (n < 928) return Bv[(size_t)k * 128 + (n - 800)];
    if (n < 1024) return 0.f;
    return Wo[(size_t)k * 1024 + (n - 1024)];
}

__global__ __launch_bounds__(256) void pack_wT_kernel(const float* __restrict__ Aq,
                                                      const float* __restrict__ Bq,
                                                      const float* __restrict__ Ak,
                                                      const float* __restrict__ Bk,
                                                      const float* __restrict__ Av,
                                                      const float* __restrict__ Bv,
                                                      const float* __restrict__ Wo,
                                                      __hip_bfloat16* __restrict__ outBase) {
    __shared__ float tile[64][65];
    int k0 = blockIdx.x * 64, n0 = blockIdx.y * 64;
    int tid = threadIdx.x;
#pragma unroll
    for (int p = 0; p < 16; ++p) {
        int idx = p * 256 + tid;       // 0..4095
        int kl = idx >> 6, nl = idx & 63;
        tile[kl][nl] = wsrc(n0 + nl, k0 + kl, Aq, Bq, Ak, Bk, Av, Bv, Wo);
    }
    __syncthreads();
#pragma unroll
    for (int p = 0; p < 16; ++p) {
        int idx = p * 256 + tid;
        int nl = idx >> 6, kl = idx & 63;
        outBase[(size_t)(n0 + nl) * 1024 + k0 + kl] = __float2bfloat16(tile[kl][nl]);
    }
}

// ---------------------------------------------------------------- fused q/k/v projection GEMM
// A is fp32 (raw inputs), converted to bf16 during LDS staging. C tile 128m x 64n.
// grid.x = 16 col-tiles (8 q, 4 k, 4 v), grid.y = 32 row-tiles. 4 waves in 2x2 (wave 64m x 32n).
__global__ __launch_bounds__(256) void gemm3_kernel(const float* __restrict__ q,
                                                    const float* __restrict__ k,
                                                    const float* __restrict__ v,
                                                    const __hip_bfloat16* __restrict__ WT,
                                                    float* __restrict__ Pq,
                                                    float* __restrict__ Pk,
                                                    float* __restrict__ Pv) {
    __shared__ __align__(16) __hip_bfloat16 As[128][72];
    __shared__ __align__(16) __hip_bfloat16 Bs[64][72];
    int t = blockIdx.x;
    const float* A; float* C; int N, n0, wrow;
    if (t < 8)       { A = q; C = Pq; N = 512; n0 = t * 64;        wrow = t * 64; }
    else if (t < 12) { A = k; C = Pk; N = 256; n0 = (t - 8) * 64;  wrow = 512 + (t - 8) * 64; }
    else             { A = v; C = Pv; N = 256; n0 = (t - 12) * 64; wrow = 768 + (t - 12) * 64; }
    int m0 = blockIdx.y * 128;
    int tid = threadIdx.x;
    int wave = tid >> 6, lane = tid & 63, quad = lane >> 4, l15 = lane & 15;
    int wm = wave >> 1, wn = wave & 1;
    floatx4 acc[4][2];
#pragma unroll
    for (int mt = 0; mt < 4; ++mt)
#pragma unroll
        for (int nt = 0; nt < 2; ++nt) acc[mt][nt] = (floatx4){0.f, 0.f, 0.f, 0.f};

    for (int k0 = 0; k0 < 1024; k0 += 64) {
#pragma unroll
        for (int pp = 0; pp < 8; ++pp) {             // A: fp32 -> bf16 inline
            int idx = pp * 256 + tid;                // 0..2047
            int row = idx >> 4, c4 = (idx & 15) * 4;
            float4 av = *(const float4*)(A + (size_t)(m0 + row) * 1024 + k0 + c4);
            ushort4 bv;
            bv.x = bfbits(av.x); bv.y = bfbits(av.y); bv.z = bfbits(av.z); bv.w = bfbits(av.w);
            *(ushort4*)&As[row][c4] = bv;
        }
#pragma unroll
        for (int pp = 0; pp < 2; ++pp) {             // B: packed bf16 weights
            int idx = pp * 256 + tid;                // 0..511
            int row = idx >> 3, c8 = (idx & 7) * 8;
            *(uint4*)&Bs[row][c8] = *(const uint4*)(WT + (size_t)(wrow + row) * 1024 + k0 + c8);
        }
        __syncthreads();
#pragma unroll
        for (int ks = 0; ks < 64; ks += 32) {
            short8 af[4], bf[2];
#pragma unroll
            for (int t2 = 0; t2 < 4; ++t2)
                af[t2] = *(const short8*)&As[wm * 64 + t2 * 16 + l15][ks + quad * 8];
#pragma unroll
            for (int t2 = 0; t2 < 2; ++t2)
                bf[t2] = *(const short8*)&Bs[wn * 32 + t2 * 16 + l15][ks + quad * 8];
#pragma unroll
            for (int mt = 0; mt < 4; ++mt)
#pragma unroll
                for (int nt = 0; nt < 2; ++nt)
                    acc[mt][nt] = MFMA16(af[mt], bf[nt], acc[mt][nt]);
        }
        __syncthreads();
    }
#pragma unroll
    for (int mt = 0; mt < 4; ++mt)
#pragma unroll
        for (int nt = 0; nt < 2; ++nt)
#pragma unroll
            for (int r = 0; r < 4; ++r) {
                int row = m0 + wm * 64 + mt * 16 + quad * 4 + r;
                int col = n0 + wn * 32 + nt * 16 + l15;
                C[(size_t)row * N + col] = acc[mt][nt][r];
            }
}

// ---------------------------------------------------------------- output GEMM: out = att @ WoT^T
// A bf16 [4096 x 1024], BT = WoT rows (1024 x 1024), C fp32. Tile 128m x 64n, grid (16, 32).
__global__ __launch_bounds__(256) void gemm_out_kernel(const __hip_bfloat16* __restrict__ A,
                                                       const __hip_bfloat16* __restrict__ BT,
                                                       float* __restrict__ C) {
    __shared__ __align__(16) __hip_bfloat16 As[128][72];
    __shared__ __align__(16) __hip_bfloat16 Bs[64][72];
    int n0 = blockIdx.x * 64, m0 = blockIdx.y * 128;
    int tid = threadIdx.x;
    int wave = tid >> 6, lane = tid & 63, quad = lane >> 4, l15 = lane & 15;
    int wm = wave >> 1, wn = wave & 1;
    floatx4 acc[4][2];
#pragma unroll
    for (int mt = 0; mt < 4; ++mt)
#pragma unroll
        for (int nt = 0; nt < 2; ++nt) acc[mt][nt] = (floatx4){0.f, 0.f, 0.f, 0.f};

    for (int k0 = 0; k0 < 1024; k0 += 64) {
#pragma unroll
        for (int pp = 0; pp < 4; ++pp) {
            int idx = pp * 256 + tid;                // 0..1023
            int row = idx >> 3, c8 = (idx & 7) * 8;
            *(uint4*)&As[row][c8] = *(const uint4*)(A + (size_t)(m0 + row) * 1024 + k0 + c8);
        }
#pragma unroll
        for (int pp = 0; pp < 2; ++pp) {
            int idx = pp * 256 + tid;                // 0..511
            int row = idx >> 3, c8 = (idx & 7) * 8;
            *(uint4*)&Bs[row][c8] = *(const uint4*)(BT + (size_t)(n0 + row) * 1024 + k0 + c8);
        }
        __syncthreads();
#pragma unroll
        for (int ks = 0; ks < 64; ks += 32) {
            short8 af[4], bf[2];
#pragma unroll
            for (int t2 = 0; t2 < 4; ++t2)
                af[t2] = *(const short8*)&As[wm * 64 + t2 * 16 + l15][ks + quad * 8];
#pragma unroll
            for (int t2 = 0; t2 < 2; ++t2)
                bf[t2] = *(const short8*)&Bs[wn * 32 + t2 * 16 + l15][ks + quad * 8];
#pragma unroll
            for (int mt = 0; mt < 4; ++mt)
#pragma unroll
                for (int nt = 0; nt < 2; ++nt)
                    acc[mt][nt] = MFMA16(af[mt], bf[nt], acc[mt][nt]);
        }
        __syncthreads();
    }
#pragma unroll
    for (int mt = 0; mt < 4; ++mt)
#pragma unroll
        for (int nt = 0; nt < 2; ++nt)
#pragma unroll
            for (int r = 0; r < 4; ++r) {
                int row = m0 + wm * 64 + mt * 16 + quad * 4 + r;
                int col = n0 + wn * 32 + nt * 16 + l15;
                C[(size_t)row * 1024 + col] = acc[mt][nt][r];
            }
}

// ---------------------------------------------------------------- combine: rank contraction + RoPE
// qh folds 1/QR * 1/RANK(kh) * 1/DK * log2(e)  (softmax runs in exp2 domain)
__global__ __launch_bounds__(256) void combine_rope_kernel(const float* __restrict__ Pq,
                                                           const float* __restrict__ Pk,
                                                           const float* __restrict__ Pv,
                                                           __hip_bfloat16* __restrict__ qh,
                                                           __hip_bfloat16* __restrict__ kh,
                                                           __hip_bfloat16* __restrict__ vh) {
    int t = blockIdx.x, tid = threadIdx.x;
    int b = t >> 11, s = t & 2047;
    __shared__ float Lq[512], Lk[256], Lv[256];
    for (int i = tid; i < 512; i += 256) Lq[i] = Pq[(size_t)t * 512 + i];
    Lk[tid] = Pk[(size_t)t * 256 + tid];
    Lv[tid] = Pv[(size_t)t * 256 + tid];
    __syncthreads();
    // RoPE angle = s * 10000^(-d/32); HW v_sin/v_cos take revolutions.
    if (tid < 192) {  // 6 rows x 32 pairs of B_q
        int r = tid >> 5, d = tid & 31;
        float inv = __expf(-(float)d * 0.28782313662425576f);     // ln(10000)/32
        float rev = (float)s * inv * 0.15915494309189535f;        // /2pi
        rev -= floorf(rev);
        float sn = __builtin_amdgcn_sinf(rev);
        float cs = __builtin_amdgcn_cosf(rev);
        float x1 = Lq[96 + r * 64 + d], x2 = Lq[96 + r * 64 + d + 32];
        Lq[96 + r * 64 + d] = x1 * cs + x2 * sn;
        Lq[96 + r * 64 + d + 32] = -x1 * sn + x2 * cs;
    } else {          // 2 rows x 32 pairs of B_k
        int i2 = tid - 192;
        int r = i2 >> 5, d = i2 & 31;
        float inv = __expf(-(float)d * 0.28782313662425576f);
        float rev = (float)s * inv * 0.15915494309189535f;
        rev -= floorf(rev);
        float sn = __builtin_amdgcn_sinf(rev);
        float cs = __builtin_amdgcn_cosf(rev);
        float x1 = Lk[32 + r * 64 + d], x2 = Lk[32 + r * 64 + d + 32];
        Lk[32 + r * 64 + d] = x1 * cs + x2 * sn;
        Lk[32 + r * 64 + d + 32] = -x1 * sn + x2 * cs;
    }
    __syncthreads();
    const float QSCALE = 1.4426950408889634f / 768.0f;  // log2(e) / (QR*RANK*DK)
    int bh0 = b * 16;
    for (int i = tid; i < 1024; i += 256) {
        int h = i >> 6, d = i & 63;
        float aq = 0.f;
#pragma unroll
        for (int r = 0; r < 6; ++r) aq += Lq[h * 6 + r] * Lq[96 + r * 64 + d];
        size_t o = ((size_t)(bh0 + h) * 2048 + s) * 64 + d;
        qh[o] = __float2bfloat16(aq * QSCALE);
        float ak = Lk[h * 2] * Lk[32 + d] + Lk[h * 2 + 1] * Lk[96 + d];
        kh[o] = __float2bfloat16(ak);
        float av = Lv[h * 2] * Lv[32 + d] + Lv[h * 2 + 1] * Lv[96 + d];
        vh[o] = __float2bfloat16(av * 0.5f);
    }
}

// ---------------------------------------------------------------- V transpose: vh[bh][s][d] -> vT[bh][d][s]
__global__ __launch_bounds__(256) void transpose_v_kernel(const __hip_bfloat16* __restrict__ vh,
                                                          __hip_bfloat16* __restrict__ vT) {
    __shared__ __hip_bfloat16 tile[64][65];
    int s0 = blockIdx.x * 64, bh = blockIdx.y;
    int tid = threadIdx.x;
#pragma unroll
    for (int p = 0; p < 16; ++p) {
        int idx = p * 256 + tid;
        int r = idx >> 6, c = idx & 63;
        tile[r][c] = vh[((size_t)bh * 2048 + s0 + r) * 64 + c];
    }
    __syncthreads();
#pragma unroll
    for (int p = 0; p < 16; ++p) {
        int idx = p * 256 + tid;
        int r = idx >> 6, c = idx & 63;  // r = d, c = local s
        vT[((size_t)bh * 64 + r) * 2048 + s0 + c] = tile[c][r];
    }
}

// ---------------------------------------------------------------- causal flash attention, Q-tile 128
// Static-max softmax (scores O(0.1), /768+log2e folded into qh): no max shift, no rescale.
// grid 512 blocks: 16 q-tiles(128 rows) x 32 bh, XCD-affine bh, heavy-first.
// 4 waves; wave owns 2 strips of 16 q-rows. Each K/V stage (64-wide) feeds 32 MFMA.
__global__ __launch_bounds__(256) void flash_kernel(const __hip_bfloat16* __restrict__ qh,
                                                    const __hip_bfloat16* __restrict__ kh,
                                                    const __hip_bfloat16* __restrict__ vT,
                                                    __hip_bfloat16* __restrict__ att) {
    int lin = blockIdx.x + (blockIdx.y << 4);           // 0..511
    int bh = ((lin & 7) << 2) | ((lin >> 3) & 3);       // XCD-affine head mapping
    int p = 15 - (lin >> 5);                            // heavy q-tiles first
    int tid = threadIdx.x;
    int wave = tid >> 6, lane = tid & 63, quad = lane >> 4, l15 = lane & 15;
    int q0 = p * 128;
    __shared__ __align__(16) __hip_bfloat16 Ks[64][72];       // K[kidx][d]
    __shared__ __align__(16) __hip_bfloat16 Vts[64][72];      // V^T[d][kidx]
    __shared__ __align__(16) __hip_bfloat16 Ps[4][32][72];    // per-wave P strips (2x16 rows)

    short8 aq[2][2];
#pragma unroll
    for (int m = 0; m < 2; ++m) {
        const __hip_bfloat16* qrow =
            qh + ((size_t)bh * 2048 + q0 + wave * 32 + m * 16 + l15) * 64 + quad * 8;
        aq[m][0] = *(const short8*)(qrow);
        aq[m][1] = *(const short8*)(qrow + 32);
    }

    floatx4 o[2][4];
#pragma unroll
    for (int m = 0; m < 2; ++m)
#pragma unroll
        for (int nt = 0; nt < 4; ++nt) o[m][nt] = (floatx4){0.f, 0.f, 0.f, 0.f};
    float rs[2][4] = {{0.f, 0.f, 0.f, 0.f}, {0.f, 0.f, 0.f, 0.f}};

    int jmax = 2 * p + 1;
    for (int j = 0; j <= jmax; ++j) {
        int k0 = j * 64;
#pragma unroll
        for (int pp = 0; pp < 2; ++pp) {
            int idx = pp * 256 + tid;  // 0..511
            int row = idx >> 3, c8 = (idx & 7) * 8;
            *(uint4*)&Ks[row][c8] = *(const uint4*)(kh + ((size_t)bh * 2048 + k0 + row) * 64 + c8);
            *(uint4*)&Vts[row][c8] = *(const uint4*)(vT + ((size_t)bh * 64 + row) * 2048 + k0 + c8);
        }
        __syncthreads();

        int krel = j - 2 * p;  // >=0 only in the diagonal 128x128 block
        bool skip0 = (krel == 1) && (wave * 32 < 64);            // strip fully masked
        bool skip1 = (krel == 1) && (wave * 32 + 16 < 64);

        // S = Q @ K^T for both strips, sharing K-frag reads
        floatx4 s[2][4];
#pragma unroll
        for (int m = 0; m < 2; ++m)
#pragma unroll
            for (int nt = 0; nt < 4; ++nt) s[m][nt] = (floatx4){0.f, 0.f, 0.f, 0.f};
#pragma unroll
        for (int nt = 0; nt < 4; ++nt) {
            short8 bk0 = *(const short8*)&Ks[nt * 16 + l15][quad * 8];
            short8 bk1 = *(const short8*)&Ks[nt * 16 + l15][32 + quad * 8];
            if (!skip0) {
                s[0][nt] = MFMA16(aq[0][0], bk0, s[0][nt]);
                s[0][nt] = MFMA16(aq[0][1], bk1, s[0][nt]);
            }
            if (!skip1) {
                s[1][nt] = MFMA16(aq[1][0], bk0, s[1][nt]);
                s[1][nt] = MFMA16(aq[1][1], bk1, s[1][nt]);
            }
        }
#pragma unroll
        for (int m = 0; m < 2; ++m) {
            bool skip = m == 0 ? skip0 : skip1;
            if (skip) continue;
            int sbase = wave * 32 + m * 16;  // strip's local q-row base
            bool domask = (krel >= 0) && (krel * 64 + 63 > sbase);
            if (domask) {
#pragma unroll
                for (int nt = 0; nt < 4; ++nt) {
                    int kcol = k0 + nt * 16 + l15;
#pragma unroll
                    for (int r = 0; r < 4; ++r)
                        if (kcol > q0 + sbase + quad * 4 + r) s[m][nt][r] = -__builtin_inff();
                }
            }
            // p = exp2(s); per-lane row-sum; C-layout -> LDS strip
#pragma unroll
            for (int nt = 0; nt < 4; ++nt)
#pragma unroll
                for (int r = 0; r < 4; ++r) {
                    float pe = exp2f(s[m][nt][r]);
                    rs[m][r] += pe;
                    Ps[wave][m * 16 + quad * 4 + r][nt * 16 + l15] = __float2bfloat16(pe);
                }
        }
        __builtin_amdgcn_s_waitcnt(0xC07F);  // lgkmcnt(0): own-wave DS ordering
        // O += P @ V, sharing V-frag reads across strips
        short8 pa[2][2];
#pragma unroll
        for (int m = 0; m < 2; ++m) {
            pa[m][0] = *(const short8*)&Ps[wave][m * 16 + l15][quad * 8];
            pa[m][1] = *(const short8*)&Ps[wave][m * 16 + l15][32 + quad * 8];
        }
#pragma unroll
        for (int nt = 0; nt < 4; ++nt) {
            short8 bv0 = *(const short8*)&Vts[nt * 16 + l15][quad * 8];
            short8 bv1 = *(const short8*)&Vts[nt * 16 + l15][32 + quad * 8];
            if (!skip0) {
                o[0][nt] = MFMA16(pa[0][0], bv0, o[0][nt]);
                o[0][nt] = MFMA16(pa[0][1], bv1, o[0][nt]);
            }
            if (!skip1) {
                o[1][nt] = MFMA16(pa[1][0], bv0, o[1][nt]);
                o[1][nt] = MFMA16(pa[1][1], bv1, o[1][nt]);
            }
        }
        __syncthreads();  // Ks/Vts consumed; next iter restages
    }
    // final row-sum reduction + epilogue per strip
    int b = bh >> 4, h = bh & 15;
#pragma unroll
    for (int m = 0; m < 2; ++m) {
        float l_i[4];
#pragma unroll
        for (int r = 0; r < 4; ++r) {
            float x = rs[m][r];
            x += __shfl_xor(x, 1, 64);
            x += __shfl_xor(x, 2, 64);
            x += __shfl_xor(x, 4, 64);
            x += __shfl_xor(x, 8, 64);
            l_i[r] = x;
        }
        size_t obase = ((size_t)b * 2048 + q0 + wave * 32 + m * 16 + quad * 4) * 1024 + h * 64;
#pragma unroll
        for (int nt = 0; nt < 4; ++nt)
#pragma unroll
            for (int r = 0; r < 4; ++r)
                att[obase + (size_t)r * 1024 + nt * 16 + l15] = __float2bfloat16(o[m][nt][r] / l_i[r]);
    }
}

// ---------------------------------------------------------------- launch
extern "C" void kernel_launch(void* const* d_in, const int* in_sizes, int n_in,
                              void* d_out, int out_size, void* d_ws, size_t ws_size,
                              hipStream_t stream) {
    const float* q = (const float*)d_in[0];
    const float* k = (const float*)d_in[1];
    const float* v = (const float*)d_in[2];
    // d_in[3] = causal mask (ignored; computed analytically)
    const float* W_Aq = (const float*)d_in[4];
    const float* W_Ak = (const float*)d_in[5];
    const float* W_Av = (const float*)d_in[6];
    const float* W_Bq = (const float*)d_in[7];
    const float* W_Bk = (const float*)d_in[8];
    const float* W_Bv = (const float*)d_in[9];
    const float* Wo = (const float*)d_in[10];
    float* out = (float*)d_out;

    char* w = (char*)d_ws;
    __hip_bfloat16* qh = (__hip_bfloat16*)(w + 0);          // 8.4 MB
    __hip_bfloat16* khp = (__hip_bfloat16*)(w + 8388608);
    __hip_bfloat16* vhN = (__hip_bfloat16*)(w + 16777216);
    __hip_bfloat16* WT = (__hip_bfloat16*)(w + 25165824);   // packed 2048x1024 bf16
    __hip_bfloat16* WoT = (__hip_bfloat16*)(w + 27262976);  // rows 1024..2047 of WT
    float* Pq = (float*)(w + 29360128);  // 4096 x 512
    float* Pk = (float*)(w + 37748736);  // 4096 x 256
    float* Pv = (float*)(w + 41943040);  // 4096 x 256
    __hip_bfloat16* att = (__hip_bfloat16*)(w + 29360128);  // over dead Pq
    __hip_bfloat16* vT = (__hip_bfloat16*)(w + 37748736);   // over dead Pk/Pv

    pack_wT_kernel<<<dim3(16, 32), 256, 0, stream>>>(W_Aq, W_Bq, W_Ak, W_Bk, W_Av, W_Bv, Wo, WT);
    gemm3_kernel<<<dim3(16, 32), 256, 0, stream>>>(q, k, v, WT, Pq, Pk, Pv);
    combine_rope_kernel<<<4096, 256, 0, stream>>>(Pq, Pk, Pv, qh, khp, vhN);
    transpose_v_kernel<<<dim3(32, 32), 256, 0, stream>>>(vhN, vT);
    flash_kernel<<<dim3(16, 32), 256, 0, stream>>>(qh, khp, vT, att);
    gemm_out_kernel<<<dim3(16, 32), 256, 0, stream>>>(att, WoT, out);
}